// Round 4
// baseline (296.460 us; speedup 1.0000x reference)
//
#include <hip/hip_runtime.h>
#include <hip/hip_bf16.h>

// ChebyshevKANLayer: y[b,o] = sum_{i,j} T_j(xhat[b,i]) * C[i,o,j]
// T0==1 folded into fp32 bias; GEMM K = 1024*8 = 8192 (degrees 1..8), bf16 MFMA.
// R10: A is never materialized. R9 showed gemm=129us but 147us outside it;
// build_a's 134MB write + gemm's 134MB read (~42us HBM) + a launch are pure
// overhead for data derivable from x (1 float -> 8 bf16 via 7 FMAs). New:
//   rowstats kernel: per-row (scale, offset), 64 KB.
//   gemm stages A on the fly: load x[row][it*8+scol] (pre-swizzled i, same XOR
//   scheme), Chebyshev recurrence, pack uint4, ds_write_b128 to the exact LDS
//   address the DMA used. Read side / swizzle untouched. B keeps DMA staging,
//   counted vmcnt(2). x-loads for tile it+2 issue at tile-it top (T14 split);
//   compute+write lands between the two MFMA phases.
//   BM=256 x BN=128, BK=64, 512 thr (8 waves 4Mx2N), 3 x 48KB LDS, 1 bar/tile.
// ws: bias 4KB(pad 64K) | rowstats 64KB | B^T 16.8MB   (A2 gone: 151->17 MB)

typedef __attribute__((ext_vector_type(8))) short bf16x8s;   // MFMA A/B frag (4 VGPRs)
typedef __attribute__((ext_vector_type(4))) float f32x4;     // MFMA C/D frag

constexpr int BROWS = 8192;
constexpr int IDIM  = 1024;
constexpr int ODIM  = 1024;
constexpr int DEG1  = 9;
constexpr int KP    = 8;             // stored degrees 1..8 per input i
constexpr int KD    = IDIM * KP;     // 8192

__device__ __forceinline__ ushort f2bf(float f) {
  return ((__hip_bfloat16_raw)__float2bfloat16(f)).x;
}

// async global->LDS, 16 B per lane. LDS dst MUST be wave-uniform base + lane*16.
__device__ __forceinline__ void gload_lds16(const void* g, void* l) {
  __builtin_amdgcn_global_load_lds(
      (const __attribute__((address_space(1))) unsigned int*)g,
      (__attribute__((address_space(3))) unsigned int*)l, 16, 0, 0);
}

// ---------- 0. zero the bias accumulator (ws is poisoned every call) ----------
__global__ __launch_bounds__(256) void zero_bias_kernel(float* __restrict__ bias) {
  bias[blockIdx.x * 256 + threadIdx.x] = 0.0f;
}

// ---------- 1. rowstats: per-row scale/offset for xhat = sc*x + of ----------
__global__ __launch_bounds__(256) void rowstats_kernel(const float* __restrict__ x,
                                                       float2* __restrict__ stats) {
  __shared__ float red[8];
  const int b = blockIdx.x, t = threadIdx.x, lane = t & 63, wv = t >> 6;
  const float4 v = ((const float4*)(x + (size_t)b * IDIM))[t];
  float mn = fminf(fminf(v.x, v.y), fminf(v.z, v.w));
  float mx = fmaxf(fmaxf(v.x, v.y), fmaxf(v.z, v.w));
#pragma unroll
  for (int off = 32; off >= 1; off >>= 1) {
    mn = fminf(mn, __shfl_xor(mn, off));
    mx = fmaxf(mx, __shfl_xor(mx, off));
  }
  if (lane == 0) { red[wv] = mn; red[4 + wv] = mx; }
  __syncthreads();
  if (t == 0) {
    mn = fminf(fminf(red[0], red[1]), fminf(red[2], red[3]));
    mx = fmaxf(fmaxf(red[4], red[5]), fmaxf(red[6], red[7]));
    const float sc = 2.0f / (mx - mn);
    stats[b] = (float2){sc, -mn * sc - 1.0f};
  }
}

// ---------- 2. B^T[o][i*8+d'] = C[i][o][d'+1] bf16; j==0 -> fp32 bias ----------
__global__ __launch_bounds__(256) void build_b_kernel(const float* __restrict__ coeffs,
                                                      ushort* __restrict__ B2T,
                                                      float* __restrict__ bias) {
  __shared__ __align__(16) ushort tile[64 * 256];          // 32 KB [o_l][i_l*8+d']
  __shared__ float lb[64];
  const int i0 = blockIdx.x * 32;
  const int o0 = blockIdx.y * 64;
  const int t  = threadIdx.x;
  if (t < 64) lb[t] = 0.0f;
  __syncthreads();
  for (int idx = t; idx < 18432; idx += 256) {             // coalesced float reads
    const int i_l = idx / 576;                             // 576 = 64*9
    const int rem = idx - i_l * 576;                       // = o_l*9 + j
    const float v = coeffs[((size_t)(i0 + i_l) * ODIM + o0) * DEG1 + rem];
    const int o_l = rem / 9;
    const int j   = rem - o_l * 9;
    if (j == 0) atomicAdd(&lb[o_l], v);                    // exact fp32 bias path
    else tile[o_l * 256 + i_l * KP + (j - 1)] = f2bf(v);
  }
  __syncthreads();
  for (int idx = t; idx < 2048; idx += 256) {              // coalesced uint4 writes
    const int o_l = idx >> 5;
    const int w   = idx & 31;
    uint4* gdst = (uint4*)(B2T + (size_t)(o0 + o_l) * KD + i0 * KP);
    gdst[w] = ((const uint4*)tile)[idx];
  }
  if (t < 64) atomicAdd(&bias[o0 + t], lb[t]);             // device-scope fp32 add
}

// ---------- 3. GEMM: 256x128, BK=64, A computed on the fly, ONE barrier/tile --
// Buffers: reads hit cur; A-compute ds_writes + B-DMA hit nb (tile it+2's
// buffer = tile it-1's, consumed). x-loads for it+2 issue at tile top; the
// compute+ds_write sits between MFMA phase0 and phase1 (HBM latency hidden).
// End of tile: vmcnt(2) (B(it+1) complete, B(it+2) in flight) + lgkmcnt(0)
// (A ds_writes drained) + s_barrier.
__global__ __launch_bounds__(512, 1) void gemm_kernel(const float* __restrict__ x,
                                                      const float2* __restrict__ stats,
                                                      const ushort* __restrict__ B2T,
                                                      const float* __restrict__ bias,
                                                      float* __restrict__ out) {
  constexpr int BK    = 64;
  constexpr int KT    = KD / BK;       // 128 K-tiles
  constexpr int ABUF  = 256 * BK;      // 16384 ushorts = 32 KB
  constexpr int BBUF  = 128 * BK;      //  8192 ushorts = 16 KB
  constexpr int BUFSZ = ABUF + BBUF;   // 24576 ushorts = 48 KB
  __shared__ __align__(16) ushort Sm[3 * BUFSZ];   // 144 KB -> 1 block/CU

  const int t    = threadIdx.x;
  const int lane = t & 63;
  const int wave = t >> 6;
  const int wr   = wave >> 1;          // 0..3 : M sub-block (64 rows each)
  const int wc   = wave & 1;           // 0..1 : N sub-block (64 cols each)
  const int c16  = lane & 15;
  const int quad = lane >> 4;

  // bijective XCD chunk swizzle (256 wgs % 8 == 0): XCD k -> rows 4k..4k+3, all cols
  const int orig = blockIdx.y * 8 + blockIdx.x;    // grid (8, 32), x = col fastest
  const int swz  = (orig & 7) * 32 + (orig >> 3);
  const int rowBase = (swz >> 3) * 256;
  const int colBase = (swz & 7) * 128;

  // staging geometry: thread t covers rows trow(+64a), 16B chunk t&7; global
  // chunk index XOR-permuted (scol) so the lane-linear LDS slot realizes the
  // read-side swizzle. For A: chunk scol of tile it == input i = it*8 + scol.
  const int trow = t >> 3;                         // 0..63
  const int scol = (t & 7) ^ (trow & 7);
  const float*  xB = x + (size_t)(rowBase + trow) * IDIM + scol;
  const ushort* bB = B2T + (size_t)(colBase + trow) * KD + scol * 8;
  ushort* uB = Sm + ABUF + t * 8;                  // wave-uniform base + lane*16B

  float scr[4], ofr[4];
#pragma unroll
  for (int a = 0; a < 4; ++a) {
    const float2 s = stats[rowBase + trow + 64 * a];
    scr[a] = s.x; ofr[a] = s.y;
  }

  auto loadX = [&](int it2, float xv[4]) {         // 4 coalesced-ish L2/L3 reads
#pragma unroll
    for (int a = 0; a < 4; ++a) xv[a] = xB[(size_t)a * (64 * IDIM) + it2 * 8];
  };
  auto computeA = [&](int buf, const float xv[4]) {
#pragma unroll
    for (int a = 0; a < 4; ++a) {
      const float xn = fmaf(scr[a], xv[a], ofr[a]);
      const float T2 = 2.f * xn * xn - 1.f;
      const float T3 = 2.f * xn * T2 - xn;
      const float T4 = 2.f * xn * T3 - T2;
      const float T5 = 2.f * xn * T4 - T3;
      const float T6 = 2.f * xn * T5 - T4;
      const float T7 = 2.f * xn * T6 - T5;
      const float T8 = 2.f * xn * T7 - T6;
      uint4 w;
      w.x = (uint)f2bf(xn) | ((uint)f2bf(T2) << 16);
      w.y = (uint)f2bf(T3) | ((uint)f2bf(T4) << 16);
      w.z = (uint)f2bf(T5) | ((uint)f2bf(T6) << 16);
      w.w = (uint)f2bf(T7) | ((uint)f2bf(T8) << 16);
      *(uint4*)&Sm[buf * BUFSZ + a * 4096 + t * 8] = w;    // ds_write_b128
    }
  };
  auto issB = [&](int buf, size_t ko, int b2) {
    gload_lds16(bB + (size_t)b2 * (64 * KD) + ko, uB + buf * BUFSZ + b2 * 4096);
  };

  // per-wave LDS read offsets (ushort idx); swizzled col-chunk for kh=0/1
  const int aoff = (wr * 64 + c16) * BK;
  const int boff = (wc * 64 + c16) * BK;
  const int cx0  = ((0 + quad) ^ (c16 & 7)) * 8;
  const int cx1  = ((4 + quad) ^ (c16 & 7)) * 8;

  f32x4 acc[4][4];
#pragma unroll
  for (int m = 0; m < 4; ++m)
#pragma unroll
    for (int n = 0; n < 4; ++n) acc[m][n] = (f32x4){0.f, 0.f, 0.f, 0.f};

  // prologue: A(0),A(1) computed+written; B(0),B(1) DMA-staged
  {
    float xv[4];
    loadX(0, xv); computeA(0, xv);
    loadX(1, xv); computeA(1, xv);
  }
  issB(0, 0, 0); issB(0, 0, 1);
  issB(1, BK, 0); issB(1, BK, 1);
  asm volatile("s_waitcnt vmcnt(2) lgkmcnt(0)" ::: "memory");  // B(0)+A writes done
  __builtin_amdgcn_s_barrier();

  int cur = 0;
  for (int it = 0; it < KT; ++it) {
    const ushort* Asb = Sm + cur * BUFSZ;
    const ushort* Bsb = Asb + ABUF;
    const int nb = (cur >= 1) ? cur - 1 : 2;       // (cur+2)%3: held tile it-1
    const size_t ko = (size_t)(it + 2) * BK;
    const bool pf = (it < KT - 2);

    float xv[4];
    if (pf) loadX(it + 2, xv);                     // issue early; consume mid-tile

    {                                              // ---- phase 0 (k 0..31) ----
      bf16x8s afr[4], bfr[4];
#pragma unroll
      for (int m = 0; m < 4; ++m)
        afr[m] = *(const bf16x8s*)&Asb[aoff + m * (16 * 64) + cx0];
#pragma unroll
      for (int n = 0; n < 4; ++n)
        bfr[n] = *(const bf16x8s*)&Bsb[boff + n * (16 * 64) + cx0];
      if (pf) { issB(nb, ko, 0); issB(nb, ko, 1); }
      __builtin_amdgcn_s_setprio(1);
#pragma unroll
      for (int m = 0; m < 4; ++m)
#pragma unroll
        for (int n = 0; n < 4; ++n)
          acc[m][n] = __builtin_amdgcn_mfma_f32_16x16x32_bf16(afr[m], bfr[n],
                                                              acc[m][n], 0, 0, 0);
      __builtin_amdgcn_s_setprio(0);
    }

    if (pf) computeA(nb, xv);                      // VALU + 4x ds_write_b128 -> nb

    {                                              // ---- phase 1 (k 32..63) ----
      bf16x8s afr[4], bfr[4];
#pragma unroll
      for (int m = 0; m < 4; ++m)
        afr[m] = *(const bf16x8s*)&Asb[aoff + m * (16 * 64) + cx1];
#pragma unroll
      for (int n = 0; n < 4; ++n)
        bfr[n] = *(const bf16x8s*)&Bsb[boff + n * (16 * 64) + cx1];
      __builtin_amdgcn_s_setprio(1);
#pragma unroll
      for (int m = 0; m < 4; ++m)
#pragma unroll
        for (int n = 0; n < 4; ++n)
          acc[m][n] = __builtin_amdgcn_mfma_f32_16x16x32_bf16(afr[m], bfr[n],
                                                              acc[m][n], 0, 0, 0);
      __builtin_amdgcn_s_setprio(0);
    }

    if (pf)              { asm volatile("s_waitcnt vmcnt(2)" ::: "memory"); }
    else if (it == KT-2) { asm volatile("s_waitcnt vmcnt(0)" ::: "memory"); }
    asm volatile("s_waitcnt lgkmcnt(0)" ::: "memory");   // A ds_writes drained
    __builtin_amdgcn_s_barrier();                  // ONE barrier per K-tile

    cur = (cur == 2) ? 0 : cur + 1;
  }

  // ---- epilogue: straight from registers, add bias ----
#pragma unroll
  for (int n = 0; n < 4; ++n) {
    const int col = colBase + wc * 64 + n * 16 + c16;
    const float bv = bias[col];
#pragma unroll
    for (int m = 0; m < 4; ++m) {
      const int r0 = rowBase + wr * 64 + m * 16 + quad * 4;
#pragma unroll
      for (int r = 0; r < 4; ++r)
        out[(size_t)(r0 + r) * ODIM + col] = acc[m][n][r] + bv;
    }
  }
}

extern "C" void kernel_launch(void* const* d_in, const int* in_sizes, int n_in,
                              void* d_out, int out_size, void* d_ws, size_t ws_size,
                              hipStream_t stream) {
  const float* x      = (const float*)d_in[0];   // [8192,1024] fp32
  const float* coeffs = (const float*)d_in[1];   // [1024,1024,9] fp32
  float* out = (float*)d_out;                    // [8192,1024] fp32

  char* ws = (char*)d_ws;
  float*  bias  = (float*)ws;                              // 4 KB (pad to 64K)
  float2* stats = (float2*)(ws + 65536);                   // 64 KB
  ushort* B2T   = (ushort*)(ws + 131072);                  // 16.78 MB
  // total ws: ~17 MB (A2 eliminated)

  zero_bias_kernel<<<ODIM / 256, 256, 0, stream>>>(bias);
  rowstats_kernel<<<BROWS, 256, 0, stream>>>(x, stats);
  build_b_kernel<<<dim3(IDIM / 32, ODIM / 64), 256, 0, stream>>>(coeffs, B2T, bias);
  gemm_kernel<<<dim3(ODIM / 128, BROWS / 256), 512, 0, stream>>>(x, stats, B2T, bias, out);
}